// Round 1
// baseline (157124.683 us; speedup 1.0000x reference)
//
#include <hip/hip_runtime.h>
#include <math.h>

#define T_SEQ 4096
#define I_DIM 1024
#define H_DIM 2048
#define O_DIM 512
#define G4    8192   // 4*H

// ---------------------------------------------------------------------------
// Phase 1: xg[t, perm(r)] = sum_k input[t,k]*W_ih[r,k] + b_ih[r] + b_hh[r]
// perm(r): r = g*2048 + 8*q + j  ->  t*8192 + q*32 + g*8 + j
// so that LSTM block b (=q) reads its 32 gate values contiguously.
// Tiled fp32 GEMM: 128x128 tile, BK=16, 256 threads, 8x8 microtile.
// ---------------------------------------------------------------------------
__global__ __launch_bounds__(256) void gemm_xg(
    const float* __restrict__ A, const float* __restrict__ W,
    const float* __restrict__ b_ih, const float* __restrict__ b_hh,
    float* __restrict__ xg)
{
  __shared__ __align__(16) float As[16][132];
  __shared__ __align__(16) float Bs[16][132];
  const int tid = threadIdx.x;
  const int t0 = blockIdx.y * 128;
  const int r0 = blockIdx.x * 128;
  const int tx = tid & 15, ty = tid >> 4;

  float acc[8][8];
  #pragma unroll
  for (int i = 0; i < 8; ++i)
    #pragma unroll
    for (int j = 0; j < 8; ++j) acc[i][j] = 0.f;

  for (int k0 = 0; k0 < I_DIM; k0 += 16) {
    #pragma unroll
    for (int i = 0; i < 2; ++i) {
      int lin = tid + i * 256;     // 0..511
      int row = lin >> 2;          // 0..127
      int kq  = (lin & 3) << 2;    // 0,4,8,12
      float4 va = *(const float4*)&A[(size_t)(t0 + row) * I_DIM + k0 + kq];
      As[kq+0][row] = va.x; As[kq+1][row] = va.y; As[kq+2][row] = va.z; As[kq+3][row] = va.w;
      float4 vb = *(const float4*)&W[(size_t)(r0 + row) * I_DIM + k0 + kq];
      Bs[kq+0][row] = vb.x; Bs[kq+1][row] = vb.y; Bs[kq+2][row] = vb.z; Bs[kq+3][row] = vb.w;
    }
    __syncthreads();
    #pragma unroll
    for (int kk = 0; kk < 16; ++kk) {
      float4 a0 = *(const float4*)&As[kk][ty*8];
      float4 a1 = *(const float4*)&As[kk][ty*8+4];
      float4 b0 = *(const float4*)&Bs[kk][tx*8];
      float4 b1 = *(const float4*)&Bs[kk][tx*8+4];
      float av[8] = {a0.x,a0.y,a0.z,a0.w,a1.x,a1.y,a1.z,a1.w};
      float bv[8] = {b0.x,b0.y,b0.z,b0.w,b1.x,b1.y,b1.z,b1.w};
      #pragma unroll
      for (int i = 0; i < 8; ++i)
        #pragma unroll
        for (int j = 0; j < 8; ++j)
          acc[i][j] = fmaf(av[i], bv[j], acc[i][j]);
    }
    __syncthreads();
  }

  const int rbase = r0 + tx * 8;          // multiple of 8
  const int g = rbase >> 11;              // gate 0..3 (constant over 8 cols)
  const int q = (rbase & 2047) >> 3;      // 8-row group = LSTM block id
  float bias[8];
  #pragma unroll
  for (int j = 0; j < 8; ++j) bias[j] = b_ih[rbase + j] + b_hh[rbase + j];
  #pragma unroll
  for (int i = 0; i < 8; ++i) {
    int t = t0 + ty * 8 + i;
    float* dst = &xg[(size_t)t * G4 + q * 32 + g * 8];
    float4 o0 = make_float4(acc[i][0]+bias[0], acc[i][1]+bias[1], acc[i][2]+bias[2], acc[i][3]+bias[3]);
    float4 o1 = make_float4(acc[i][4]+bias[4], acc[i][5]+bias[5], acc[i][6]+bias[6], acc[i][7]+bias[7]);
    *(float4*)&dst[0] = o0;
    *(float4*)&dst[4] = o1;
  }
}

// ---------------------------------------------------------------------------
// Phase 2: persistent LSTM recurrence. Grid 256 (1 block/CU via 84KB LDS),
// 512 threads. Block b owns h[8b..8b+7]; W_hh rows live in registers
// (128 VGPRs/thread). Per step: registers x h -> butterfly reduce -> gates
// -> write 8 h values (agent scope) -> flag sync across all blocks.
// wave wid: gate = wid>>1, half = wid&1. lane covers cols 4*lane+1024*half+256*k.
// ---------------------------------------------------------------------------
__global__ __launch_bounds__(512, 2) void lstm_seq(
    const float* __restrict__ W_hh, const float* __restrict__ xg,
    float* __restrict__ hbuf /*2*2048*/, unsigned* __restrict__ flags /*256*/)
{
  __shared__ __align__(16) float smem[21000];  // 84000 B -> forces 1 block/CU
  float* part = smem;                          // [8 waves][8 rows]

  const int tid  = threadIdx.x;
  const int b    = blockIdx.x;     // 0..255
  const int lane = tid & 63;
  const int wid  = tid >> 6;       // 0..7
  const int gate = wid >> 1;       // 0..3
  const int kh   = wid & 1;
  const int colbase = 4 * lane + 1024 * kh;

  // Load weights once: rows gate*2048 + 8b + j, 16 cols/thread as 4 x float4.
  float4 w[8][4];
  #pragma unroll
  for (int j = 0; j < 8; ++j) {
    const float* wr = &W_hh[(size_t)(gate * H_DIM + 8 * b + j) * H_DIM + colbase];
    #pragma unroll
    for (int k = 0; k < 4; ++k) w[j][k] = *(const float4*)&wr[256 * k];
  }

  float c_reg = 0.f;       // cell state, lives in threads 0..7
  bool gaveup = false;     // hang safety valve

  for (int t = 0; t < T_SEQ; ++t) {
    const float* hcur = hbuf + ((t & 1) << 11);
    float*       hnxt = hbuf + (((t + 1) & 1) << 11);

    // prefetch this step's xg for the combiner threads (independent of h)
    float xgv0 = 0.f, xgv1 = 0.f, xgv2 = 0.f, xgv3 = 0.f;
    if (tid < 8) {
      const float* xp = &xg[(size_t)t * G4 + b * 32 + tid];
      xgv0 = xp[0]; xgv1 = xp[8]; xgv2 = xp[16]; xgv3 = xp[24];
    }

    // read h (fresh: fences at loop tail invalidated caches)
    float4 h4[4];
    #pragma unroll
    for (int k = 0; k < 4; ++k) h4[k] = *(const float4*)&hcur[colbase + 256 * k];

    // per-thread partial dot for 8 rows
    float acc[8];
    #pragma unroll
    for (int j = 0; j < 8; ++j) {
      float s = 0.f;
      #pragma unroll
      for (int k = 0; k < 4; ++k) {
        s = fmaf(w[j][k].x, h4[k].x, s);
        s = fmaf(w[j][k].y, h4[k].y, s);
        s = fmaf(w[j][k].z, h4[k].z, s);
        s = fmaf(w[j][k].w, h4[k].w, s);
      }
      acc[j] = s;
    }

    // 64-lane butterfly reduce (all lanes end with all 8 row sums)
    #pragma unroll
    for (int sh = 32; sh >= 1; sh >>= 1)
      #pragma unroll
      for (int j = 0; j < 8; ++j)
        acc[j] += __shfl_xor(acc[j], sh, 64);

    // one lane per row publishes the wave's sum (static indices only)
    #pragma unroll
    for (int j = 0; j < 8; ++j)
      if (lane == j) part[wid * 8 + j] = acc[j];
    __syncthreads();

    // combine 2 half-waves per gate, apply activations, update c, emit h
    if (tid < 8) {
      float ip = part[0*8+tid] + part[1*8+tid] + xgv0;
      float fp = part[2*8+tid] + part[3*8+tid] + xgv1;
      float gp = part[4*8+tid] + part[5*8+tid] + xgv2;
      float op = part[6*8+tid] + part[7*8+tid] + xgv3;
      float iv = 1.f / (1.f + expf(-ip));
      float fv = 1.f / (1.f + expf(-fp));
      float gv = tanhf(gp);
      float ov = 1.f / (1.f + expf(-op));
      c_reg = fv * c_reg + iv * gv;
      float hv = ov * tanhf(c_reg);
      __hip_atomic_store(&hnxt[8 * b + tid], hv, __ATOMIC_RELAXED, __HIP_MEMORY_SCOPE_AGENT);
    }
    // release: flag store waits on this wave's outstanding h stores
    if (tid == 0)
      __hip_atomic_store(&flags[b], (unsigned)(t + 1), __ATOMIC_RELEASE, __HIP_MEMORY_SCOPE_AGENT);

    // each of threads 0..255 spins on one block's flag; barrier ANDs them
    if (tid < 256 && !gaveup) {
      const unsigned tgt = (unsigned)(t + 1);
      int tries = 0;
      while (__hip_atomic_load(&flags[tid], __ATOMIC_RELAXED, __HIP_MEMORY_SCOPE_AGENT) < tgt) {
        __builtin_amdgcn_s_sleep(2);
        if (++tries > (1 << 22)) { gaveup = true; break; }
      }
    }
    __syncthreads();
    __threadfence();   // acquire: invalidate L1/L2 so next h reads are fresh
  }
}

// ---------------------------------------------------------------------------
// Phase 3: out[o] = h_last . W_lin[o,:] + b_lin[o]. One wave per output.
// h_last is hbuf[0] (T=4096 even: step 4095 writes buffer 0).
// ---------------------------------------------------------------------------
__global__ __launch_bounds__(256) void proj_out(
    const float* __restrict__ W_lin, const float* __restrict__ b_lin,
    const float* __restrict__ h, float* __restrict__ out)
{
  const int tid = threadIdx.x;
  const int lane = tid & 63;
  const int w4 = tid >> 6;
  const int o = blockIdx.x * 4 + w4;
  const float* wr = &W_lin[(size_t)o * H_DIM + 4 * lane];
  const float* hr = &h[4 * lane];
  float s = 0.f;
  #pragma unroll
  for (int k = 0; k < 8; ++k) {
    float4 wv = *(const float4*)&wr[256 * k];
    float4 hv = *(const float4*)&hr[256 * k];
    s = fmaf(wv.x, hv.x, s); s = fmaf(wv.y, hv.y, s);
    s = fmaf(wv.z, hv.z, s); s = fmaf(wv.w, hv.w, s);
  }
  #pragma unroll
  for (int sh = 32; sh >= 1; sh >>= 1) s += __shfl_xor(s, sh, 64);
  if (lane == 0) out[o] = s + b_lin[o];
}

// ---------------------------------------------------------------------------
extern "C" void kernel_launch(void* const* d_in, const int* in_sizes, int n_in,
                              void* d_out, int out_size, void* d_ws, size_t ws_size,
                              hipStream_t stream)
{
  const float* input = (const float*)d_in[0];
  const float* W_ih  = (const float*)d_in[1];
  const float* W_hh  = (const float*)d_in[2];
  const float* b_ih  = (const float*)d_in[3];
  const float* b_hh  = (const float*)d_in[4];
  const float* W_lin = (const float*)d_in[5];
  const float* b_lin = (const float*)d_in[6];
  float* out = (float*)d_out;

  char* ws = (char*)d_ws;
  const size_t XG_BYTES = (size_t)T_SEQ * G4 * sizeof(float);   // 128 MB
  float*    xg    = (float*)ws;
  float*    hbuf  = (float*)(ws + XG_BYTES);                    // 2*2048 f32
  unsigned* flags = (unsigned*)(ws + XG_BYTES + 2 * H_DIM * sizeof(float));

  // zero h0 buffer (h_{-1}=0), h1, and the 256 sync flags — every launch
  hipMemsetAsync(ws + XG_BYTES, 0, 2 * H_DIM * sizeof(float) + 256 * sizeof(unsigned), stream);

  gemm_xg<<<dim3(64, 32), 256, 0, stream>>>(input, W_ih, b_ih, b_hh, xg);
  lstm_seq<<<256, 512, 0, stream>>>(W_hh, xg, hbuf, flags);
  proj_out<<<128, 256, 0, stream>>>(W_lin, b_lin, hbuf, out);
}

// Round 2
// 31113.361 us; speedup vs baseline: 5.0501x; 5.0501x over previous
//
#include <hip/hip_runtime.h>
#include <math.h>

#define T_SEQ 4096
#define I_DIM 1024
#define H_DIM 2048
#define O_DIM 512
#define G4    8192   // 4*H

// ---------------------------------------------------------------------------
// Phase 1: xg[t, perm(r)] = sum_k input[t,k]*W_ih[r,k] + b_ih[r] + b_hh[r]
// perm(r): r = g*2048 + 8*q + j  ->  t*8192 + q*32 + g*8 + j
// so that LSTM block b (=q) reads its 32 gate values contiguously.
// Tiled fp32 GEMM: 128x128 tile, BK=16, 256 threads, 8x8 microtile.
// ---------------------------------------------------------------------------
__global__ __launch_bounds__(256) void gemm_xg(
    const float* __restrict__ A, const float* __restrict__ W,
    const float* __restrict__ b_ih, const float* __restrict__ b_hh,
    float* __restrict__ xg)
{
  __shared__ __align__(16) float As[16][132];
  __shared__ __align__(16) float Bs[16][132];
  const int tid = threadIdx.x;
  const int t0 = blockIdx.y * 128;
  const int r0 = blockIdx.x * 128;
  const int tx = tid & 15, ty = tid >> 4;

  float acc[8][8];
  #pragma unroll
  for (int i = 0; i < 8; ++i)
    #pragma unroll
    for (int j = 0; j < 8; ++j) acc[i][j] = 0.f;

  for (int k0 = 0; k0 < I_DIM; k0 += 16) {
    #pragma unroll
    for (int i = 0; i < 2; ++i) {
      int lin = tid + i * 256;     // 0..511
      int row = lin >> 2;          // 0..127
      int kq  = (lin & 3) << 2;    // 0,4,8,12
      float4 va = *(const float4*)&A[(size_t)(t0 + row) * I_DIM + k0 + kq];
      As[kq+0][row] = va.x; As[kq+1][row] = va.y; As[kq+2][row] = va.z; As[kq+3][row] = va.w;
      float4 vb = *(const float4*)&W[(size_t)(r0 + row) * I_DIM + k0 + kq];
      Bs[kq+0][row] = vb.x; Bs[kq+1][row] = vb.y; Bs[kq+2][row] = vb.z; Bs[kq+3][row] = vb.w;
    }
    __syncthreads();
    #pragma unroll
    for (int kk = 0; kk < 16; ++kk) {
      float4 a0 = *(const float4*)&As[kk][ty*8];
      float4 a1 = *(const float4*)&As[kk][ty*8+4];
      float4 b0 = *(const float4*)&Bs[kk][tx*8];
      float4 b1 = *(const float4*)&Bs[kk][tx*8+4];
      float av[8] = {a0.x,a0.y,a0.z,a0.w,a1.x,a1.y,a1.z,a1.w};
      float bv[8] = {b0.x,b0.y,b0.z,b0.w,b1.x,b1.y,b1.z,b1.w};
      #pragma unroll
      for (int i = 0; i < 8; ++i)
        #pragma unroll
        for (int j = 0; j < 8; ++j)
          acc[i][j] = fmaf(av[i], bv[j], acc[i][j]);
    }
    __syncthreads();
  }

  const int rbase = r0 + tx * 8;          // multiple of 8
  const int g = rbase >> 11;              // gate 0..3 (constant over 8 cols)
  const int q = (rbase & 2047) >> 3;      // 8-row group = LSTM block id
  float bias[8];
  #pragma unroll
  for (int j = 0; j < 8; ++j) bias[j] = b_ih[rbase + j] + b_hh[rbase + j];
  #pragma unroll
  for (int i = 0; i < 8; ++i) {
    int t = t0 + ty * 8 + i;
    float* dst = &xg[(size_t)t * G4 + q * 32 + g * 8];
    float4 o0 = make_float4(acc[i][0]+bias[0], acc[i][1]+bias[1], acc[i][2]+bias[2], acc[i][3]+bias[3]);
    float4 o1 = make_float4(acc[i][4]+bias[4], acc[i][5]+bias[5], acc[i][6]+bias[6], acc[i][7]+bias[7]);
    *(float4*)&dst[0] = o0;
    *(float4*)&dst[4] = o1;
  }
}

// fast activations (only 8 threads run these, but they sit on the serial path)
__device__ __forceinline__ float sigf(float x) {
  return 1.f / (1.f + __expf(-x));
}
__device__ __forceinline__ float tanh_fast(float x) {
  // (e^2x - 1)/(e^2x + 1) = 1 - 2/(e^2x + 1); saturates correctly at +-inf
  return 1.f - 2.f / (__expf(2.f * x) + 1.f);
}

// ---------------------------------------------------------------------------
// Phase 2: persistent LSTM recurrence. Grid 256 (1 block/CU via 84KB LDS),
// 512 threads. Block b owns h[8b..8b+7]; W_hh rows live in registers.
// ALL cross-block traffic (h, flags) uses relaxed agent-scope atomics:
// global_load/store with sc0 sc1 (L1/L2 bypass, coherent at LLC). No
// release fences, no __threadfence -> no buffer_wbl2 / buffer_inv L2 tag
// scans in the loop (the round-1 killer: ~37us/step of cache maintenance).
// Ordering h-stores -> flag-store is a raw s_waitcnt vmcnt(0) in wave 0.
// ---------------------------------------------------------------------------
__global__ __launch_bounds__(512, 2) void lstm_seq(
    const float* __restrict__ W_hh, const float* __restrict__ xg,
    float* __restrict__ hbuf /*2*2048*/, unsigned* __restrict__ flags /*256*/)
{
  __shared__ __align__(16) float smem[21000];  // 84000 B -> forces 1 block/CU
  float* part = smem;                          // [8 waves][8 rows]

  const int tid  = threadIdx.x;
  const int b    = blockIdx.x;     // 0..255
  const int lane = tid & 63;
  const int wid  = tid >> 6;       // 0..7
  const int gate = wid >> 1;       // 0..3
  const int kh   = wid & 1;
  const int colbase = 4 * lane + 1024 * kh;

  // Load weights once: rows gate*2048 + 8b + j, 16 cols/thread as 4 x float4.
  float4 w[8][4];
  #pragma unroll
  for (int j = 0; j < 8; ++j) {
    const float* wr = &W_hh[(size_t)(gate * H_DIM + 8 * b + j) * H_DIM + colbase];
    #pragma unroll
    for (int k = 0; k < 4; ++k) w[j][k] = *(const float4*)&wr[256 * k];
  }

  float c_reg = 0.f;       // cell state, lives in threads 0..7
  bool gaveup = false;     // hang safety valve

  for (int t = 0; t < T_SEQ; ++t) {
    const float* hcur = hbuf + ((t & 1) << 11);
    float*       hnxt = hbuf + (((t + 1) & 1) << 11);

    // prefetch this step's xg for the combiner threads (independent of h)
    float xgv0 = 0.f, xgv1 = 0.f, xgv2 = 0.f, xgv3 = 0.f;
    if (tid < 8) {
      const float* xp = &xg[(size_t)t * G4 + b * 32 + tid];
      xgv0 = xp[0]; xgv1 = xp[8]; xgv2 = xp[16]; xgv3 = xp[24];
    }

    // read h straight from the coherent point (L1/L2 bypass) — no fence needed
    float hv16[16];
    {
      const float* hp = hcur + colbase;
      #pragma unroll
      for (int k = 0; k < 4; ++k)
        #pragma unroll
        for (int e = 0; e < 4; ++e)
          hv16[4*k+e] = __hip_atomic_load(&hp[256*k + e], __ATOMIC_RELAXED,
                                          __HIP_MEMORY_SCOPE_AGENT);
    }

    // per-thread partial dot for 8 rows
    float acc[8];
    #pragma unroll
    for (int j = 0; j < 8; ++j) {
      float s = 0.f;
      #pragma unroll
      for (int k = 0; k < 4; ++k) {
        s = fmaf(w[j][k].x, hv16[4*k+0], s);
        s = fmaf(w[j][k].y, hv16[4*k+1], s);
        s = fmaf(w[j][k].z, hv16[4*k+2], s);
        s = fmaf(w[j][k].w, hv16[4*k+3], s);
      }
      acc[j] = s;
    }

    // 64-lane butterfly reduce (all lanes end with all 8 row sums)
    #pragma unroll
    for (int sh = 32; sh >= 1; sh >>= 1)
      #pragma unroll
      for (int j = 0; j < 8; ++j)
        acc[j] += __shfl_xor(acc[j], sh, 64);

    // one lane per row publishes the wave's sum (static indices only)
    #pragma unroll
    for (int j = 0; j < 8; ++j)
      if (lane == j) part[wid * 8 + j] = acc[j];
    __syncthreads();

    // combine 2 half-waves per gate, apply activations, update c, emit h
    if (tid < 8) {
      float ip = part[0*8+tid] + part[1*8+tid] + xgv0;
      float fp = part[2*8+tid] + part[3*8+tid] + xgv1;
      float gp = part[4*8+tid] + part[5*8+tid] + xgv2;
      float op = part[6*8+tid] + part[7*8+tid] + xgv3;
      float iv = sigf(ip);
      float fv = sigf(fp);
      float gv = tanh_fast(gp);
      float ov = sigf(op);
      c_reg = fv * c_reg + iv * gv;
      float hv = ov * tanh_fast(c_reg);
      __hip_atomic_store(&hnxt[8 * b + tid], hv, __ATOMIC_RELAXED,
                         __HIP_MEMORY_SCOPE_AGENT);
    }
    // wave 0: drain the write-through h stores to the coherence point,
    // THEN publish the flag (plain relaxed store, no wbl2/inv).
    if (wid == 0) {
      asm volatile("s_waitcnt vmcnt(0)" ::: "memory");
      if (lane == 0)
        __hip_atomic_store(&flags[b], (unsigned)(t + 1), __ATOMIC_RELAXED,
                           __HIP_MEMORY_SCOPE_AGENT);
    }

    // each of threads 0..255 spins on one block's flag; barrier ANDs them
    if (tid < 256 && !gaveup) {
      const unsigned tgt = (unsigned)(t + 1);
      int tries = 0;
      while (__hip_atomic_load(&flags[tid], __ATOMIC_RELAXED,
                               __HIP_MEMORY_SCOPE_AGENT) < tgt) {
        __builtin_amdgcn_s_sleep(1);
        if (++tries > (1 << 24)) { gaveup = true; break; }
      }
    }
    __syncthreads();   // compiler+exec barrier; h reads above bypass caches
  }
}

// ---------------------------------------------------------------------------
// Phase 3: out[o] = h_last . W_lin[o,:] + b_lin[o]. One wave per output.
// h_last is hbuf[0] (T=4096 even: step 4095 writes buffer 0).
// ---------------------------------------------------------------------------
__global__ __launch_bounds__(256) void proj_out(
    const float* __restrict__ W_lin, const float* __restrict__ b_lin,
    const float* __restrict__ h, float* __restrict__ out)
{
  const int tid = threadIdx.x;
  const int lane = tid & 63;
  const int w4 = tid >> 6;
  const int o = blockIdx.x * 4 + w4;
  const float* wr = &W_lin[(size_t)o * H_DIM + 4 * lane];
  const float* hr = &h[4 * lane];
  float s = 0.f;
  #pragma unroll
  for (int k = 0; k < 8; ++k) {
    float4 wv = *(const float4*)&wr[256 * k];
    float4 hv = *(const float4*)&hr[256 * k];
    s = fmaf(wv.x, hv.x, s); s = fmaf(wv.y, hv.y, s);
    s = fmaf(wv.z, hv.z, s); s = fmaf(wv.w, hv.w, s);
  }
  #pragma unroll
  for (int sh = 32; sh >= 1; sh >>= 1) s += __shfl_xor(s, sh, 64);
  if (lane == 0) out[o] = s + b_lin[o];
}

// ---------------------------------------------------------------------------
extern "C" void kernel_launch(void* const* d_in, const int* in_sizes, int n_in,
                              void* d_out, int out_size, void* d_ws, size_t ws_size,
                              hipStream_t stream)
{
  const float* input = (const float*)d_in[0];
  const float* W_ih  = (const float*)d_in[1];
  const float* W_hh  = (const float*)d_in[2];
  const float* b_ih  = (const float*)d_in[3];
  const float* b_hh  = (const float*)d_in[4];
  const float* W_lin = (const float*)d_in[5];
  const float* b_lin = (const float*)d_in[6];
  float* out = (float*)d_out;

  char* ws = (char*)d_ws;
  const size_t XG_BYTES = (size_t)T_SEQ * G4 * sizeof(float);   // 128 MB
  float*    xg    = (float*)ws;
  float*    hbuf  = (float*)(ws + XG_BYTES);                    // 2*2048 f32
  unsigned* flags = (unsigned*)(ws + XG_BYTES + 2 * H_DIM * sizeof(float));

  // zero h0 buffer (h_{-1}=0), h1, and the 256 sync flags — every launch
  hipMemsetAsync(ws + XG_BYTES, 0, 2 * H_DIM * sizeof(float) + 256 * sizeof(unsigned), stream);

  gemm_xg<<<dim3(64, 32), 256, 0, stream>>>(input, W_ih, b_ih, b_hh, xg);
  lstm_seq<<<256, 512, 0, stream>>>(W_hh, xg, hbuf, flags);
  proj_out<<<128, 256, 0, stream>>>(W_lin, b_lin, hbuf, out);
}

// Round 3
// 25425.391 us; speedup vs baseline: 6.1798x; 1.2237x over previous
//
#include <hip/hip_runtime.h>
#include <math.h>

#define T_SEQ 4096
#define I_DIM 1024
#define H_DIM 2048
#define O_DIM 512
#define G4    8192   // 4*H

// ---------------------------------------------------------------------------
// Phase 1: xg[t, perm(r)] = sum_k input[t,k]*W_ih[r,k] + b_ih[r] + b_hh[r]
// perm(r): r = g*2048 + 8*q + j  ->  t*8192 + q*32 + g*8 + j
// so that LSTM block b (=q) reads its 32 gate values contiguously.
// Tiled fp32 GEMM: 128x128 tile, BK=16, 256 threads, 8x8 microtile.
// ---------------------------------------------------------------------------
__global__ __launch_bounds__(256) void gemm_xg(
    const float* __restrict__ A, const float* __restrict__ W,
    const float* __restrict__ b_ih, const float* __restrict__ b_hh,
    float* __restrict__ xg)
{
  __shared__ __align__(16) float As[16][132];
  __shared__ __align__(16) float Bs[16][132];
  const int tid = threadIdx.x;
  const int t0 = blockIdx.y * 128;
  const int r0 = blockIdx.x * 128;
  const int tx = tid & 15, ty = tid >> 4;

  float acc[8][8];
  #pragma unroll
  for (int i = 0; i < 8; ++i)
    #pragma unroll
    for (int j = 0; j < 8; ++j) acc[i][j] = 0.f;

  for (int k0 = 0; k0 < I_DIM; k0 += 16) {
    #pragma unroll
    for (int i = 0; i < 2; ++i) {
      int lin = tid + i * 256;     // 0..511
      int row = lin >> 2;          // 0..127
      int kq  = (lin & 3) << 2;    // 0,4,8,12
      float4 va = *(const float4*)&A[(size_t)(t0 + row) * I_DIM + k0 + kq];
      As[kq+0][row] = va.x; As[kq+1][row] = va.y; As[kq+2][row] = va.z; As[kq+3][row] = va.w;
      float4 vb = *(const float4*)&W[(size_t)(r0 + row) * I_DIM + k0 + kq];
      Bs[kq+0][row] = vb.x; Bs[kq+1][row] = vb.y; Bs[kq+2][row] = vb.z; Bs[kq+3][row] = vb.w;
    }
    __syncthreads();
    #pragma unroll
    for (int kk = 0; kk < 16; ++kk) {
      float4 a0 = *(const float4*)&As[kk][ty*8];
      float4 a1 = *(const float4*)&As[kk][ty*8+4];
      float4 b0 = *(const float4*)&Bs[kk][tx*8];
      float4 b1 = *(const float4*)&Bs[kk][tx*8+4];
      float av[8] = {a0.x,a0.y,a0.z,a0.w,a1.x,a1.y,a1.z,a1.w};
      float bv[8] = {b0.x,b0.y,b0.z,b0.w,b1.x,b1.y,b1.z,b1.w};
      #pragma unroll
      for (int i = 0; i < 8; ++i)
        #pragma unroll
        for (int j = 0; j < 8; ++j)
          acc[i][j] = fmaf(av[i], bv[j], acc[i][j]);
    }
    __syncthreads();
  }

  const int rbase = r0 + tx * 8;          // multiple of 8
  const int g = rbase >> 11;              // gate 0..3 (constant over 8 cols)
  const int q = (rbase & 2047) >> 3;      // 8-row group = LSTM block id
  float bias[8];
  #pragma unroll
  for (int j = 0; j < 8; ++j) bias[j] = b_ih[rbase + j] + b_hh[rbase + j];
  #pragma unroll
  for (int i = 0; i < 8; ++i) {
    int t = t0 + ty * 8 + i;
    float* dst = &xg[(size_t)t * G4 + q * 32 + g * 8];
    float4 o0 = make_float4(acc[i][0]+bias[0], acc[i][1]+bias[1], acc[i][2]+bias[2], acc[i][3]+bias[3]);
    float4 o1 = make_float4(acc[i][4]+bias[4], acc[i][5]+bias[5], acc[i][6]+bias[6], acc[i][7]+bias[7]);
    *(float4*)&dst[0] = o0;
    *(float4*)&dst[4] = o1;
  }
}

// fast activations (lane 0 only, but on the serial critical path)
__device__ __forceinline__ float sigf(float x) {
  return 1.f / (1.f + __expf(-x));
}
__device__ __forceinline__ float tanh_fast(float x) {
  return 1.f - 2.f / (__expf(2.f * x) + 1.f);   // saturates correctly
}

// ---------------------------------------------------------------------------
// Phase 2: persistent LSTM recurrence. Grid 256 (1 block/CU via 84KB LDS),
// 512 threads = 8 waves. Wave w owns h-element 8b+w: its 4 gate rows
// (g*2048 + 8b + w) live in registers (32 x float4 per lane). Per step:
//   1. each wave pulls a 1KB slice of h from LLC (one dwordx4/lane, sc0 sc1
//      = L1/L2 bypass, coherent at LLC) -> LDS broadcast -> barrier
//   2. ds_read_b128 columns + 128 FMAs -> butterfly reduce 4 gate sums
//   3. lane 0: activations, c update, ONE h store (sc0 sc1)
//   4. per-wave vmcnt(0) drain -> barrier -> wave 0 publishes flag
//   5. wave 0 polls all 256 flags with one dwordx4/lane; others wait at bar
// No release fences / no __threadfence anywhere -> zero L2 tag scans.
// ---------------------------------------------------------------------------
__global__ __launch_bounds__(512, 2) void lstm_seq(
    const float* __restrict__ W_hh, const float* __restrict__ xg,
    float* __restrict__ hbuf /*2*2048*/, unsigned* __restrict__ flags /*256*/)
{
  __shared__ __align__(16) float smem[21000];  // 84000 B -> forces 1 block/CU
  float* hsh = smem;                           // [2048] h broadcast buffer

  const int tid  = threadIdx.x;
  const int b    = blockIdx.x;     // 0..255
  const int lane = tid & 63;
  const int w    = tid >> 6;       // wave id = h element index within block

  // Weights: 4 gate rows of h-element 8b+w; cols 4*lane + 256*k, k=0..7.
  float4 wt[4][8];
  #pragma unroll
  for (int g = 0; g < 4; ++g) {
    const float* wr = &W_hh[(size_t)(g * H_DIM + 8 * b + w) * H_DIM + 4 * lane];
    #pragma unroll
    for (int k = 0; k < 8; ++k) wt[g][k] = *(const float4*)&wr[256 * k];
  }

  float c_reg = 0.f;          // cell state (lane 0 of each wave)
  bool gaveup = false;        // hang safety valve (wave 0)
  const unsigned* fp = &flags[4 * lane];   // wave-0 poll: 4 flags per lane

  for (int t = 0; t < T_SEQ; ++t) {
    const float* hcur = hbuf + ((t & 1) << 11);
    float*       hnxt = hbuf + (((t + 1) & 1) << 11);

    // xg for this element (same addr all lanes -> single-line loads; lane 0 uses)
    const float* xp = &xg[(size_t)t * G4 + b * 32 + w];
    float xgi = xp[0], xgf = xp[8], xgg = xp[16], xgo = xp[24];

    // 1) fetch my 1KB slice of h from the coherent point, broadcast via LDS
    float4 hs;
    const float* hp = hcur + 256 * w + 4 * lane;
    asm volatile("global_load_dwordx4 %0, %1, off sc0 sc1\n\t"
                 "s_waitcnt vmcnt(0)"
                 : "=&v"(hs) : "v"(hp) : "memory");
    *(float4*)&hsh[256 * w + 4 * lane] = hs;
    __syncthreads();

    // 2) dot products: 4 gate rows x 32 cols per lane
    float a0 = 0.f, a1 = 0.f, a2 = 0.f, a3 = 0.f;
    #pragma unroll
    for (int k = 0; k < 8; ++k) {
      float4 hv = *(const float4*)&hsh[4 * lane + 256 * k];
      a0 = fmaf(wt[0][k].x, hv.x, a0); a0 = fmaf(wt[0][k].y, hv.y, a0);
      a0 = fmaf(wt[0][k].z, hv.z, a0); a0 = fmaf(wt[0][k].w, hv.w, a0);
      a1 = fmaf(wt[1][k].x, hv.x, a1); a1 = fmaf(wt[1][k].y, hv.y, a1);
      a1 = fmaf(wt[1][k].z, hv.z, a1); a1 = fmaf(wt[1][k].w, hv.w, a1);
      a2 = fmaf(wt[2][k].x, hv.x, a2); a2 = fmaf(wt[2][k].y, hv.y, a2);
      a2 = fmaf(wt[2][k].z, hv.z, a2); a2 = fmaf(wt[2][k].w, hv.w, a2);
      a3 = fmaf(wt[3][k].x, hv.x, a3); a3 = fmaf(wt[3][k].y, hv.y, a3);
      a3 = fmaf(wt[3][k].z, hv.z, a3); a3 = fmaf(wt[3][k].w, hv.w, a3);
    }

    // butterfly reduce 4 values across 64 lanes
    #pragma unroll
    for (int sh = 32; sh >= 1; sh >>= 1) {
      a0 += __shfl_xor(a0, sh, 64);
      a1 += __shfl_xor(a1, sh, 64);
      a2 += __shfl_xor(a2, sh, 64);
      a3 += __shfl_xor(a3, sh, 64);
    }

    // 3) lane 0: gate math + single h store (write-through to LLC)
    if (lane == 0) {
      float iv = sigf(a0 + xgi);
      float fv = sigf(a1 + xgf);
      float gv = tanh_fast(a2 + xgg);
      float ov = sigf(a3 + xgo);
      c_reg = fv * c_reg + iv * gv;
      float hv = ov * tanh_fast(c_reg);
      __hip_atomic_store(&hnxt[8 * b + w], hv, __ATOMIC_RELAXED,
                         __HIP_MEMORY_SCOPE_AGENT);
    }

    // 4) drain my wave's store, then block-wide barrier
    asm volatile("s_waitcnt vmcnt(0)" ::: "memory");
    __syncthreads();

    // 5) wave 0: publish flag, then poll all 256 flags (4 per lane, dwordx4)
    if (w == 0) {
      if (lane == 0)
        __hip_atomic_store(&flags[b], (unsigned)(t + 1), __ATOMIC_RELAXED,
                           __HIP_MEMORY_SCOPE_AGENT);
      if (!gaveup) {
        const unsigned tgt = (unsigned)(t + 1);
        int tries = 0;
        for (;;) {
          uint4 f;
          asm volatile("global_load_dwordx4 %0, %1, off sc0 sc1\n\t"
                       "s_waitcnt vmcnt(0)"
                       : "=&v"(f) : "v"(fp) : "memory");
          unsigned m0 = f.x < f.y ? f.x : f.y;
          unsigned m1 = f.z < f.w ? f.z : f.w;
          unsigned m  = m0 < m1 ? m0 : m1;
          if (__all(m >= tgt)) break;
          __builtin_amdgcn_s_sleep(2);
          if (++tries > (1 << 22)) { gaveup = true; break; }
        }
      }
    }
    __syncthreads();
  }
}

// ---------------------------------------------------------------------------
// Phase 3: out[o] = h_last . W_lin[o,:] + b_lin[o]. One wave per output.
// h_last is hbuf[0] (T=4096 even: step 4095 writes buffer 0).
// ---------------------------------------------------------------------------
__global__ __launch_bounds__(256) void proj_out(
    const float* __restrict__ W_lin, const float* __restrict__ b_lin,
    const float* __restrict__ h, float* __restrict__ out)
{
  const int tid = threadIdx.x;
  const int lane = tid & 63;
  const int w4 = tid >> 6;
  const int o = blockIdx.x * 4 + w4;
  const float* wr = &W_lin[(size_t)o * H_DIM + 4 * lane];
  const float* hr = &h[4 * lane];
  float s = 0.f;
  #pragma unroll
  for (int k = 0; k < 8; ++k) {
    float4 wv = *(const float4*)&wr[256 * k];
    float4 hv = *(const float4*)&hr[256 * k];
    s = fmaf(wv.x, hv.x, s); s = fmaf(wv.y, hv.y, s);
    s = fmaf(wv.z, hv.z, s); s = fmaf(wv.w, hv.w, s);
  }
  #pragma unroll
  for (int sh = 32; sh >= 1; sh >>= 1) s += __shfl_xor(s, sh, 64);
  if (lane == 0) out[o] = s + b_lin[o];
}

// ---------------------------------------------------------------------------
extern "C" void kernel_launch(void* const* d_in, const int* in_sizes, int n_in,
                              void* d_out, int out_size, void* d_ws, size_t ws_size,
                              hipStream_t stream)
{
  const float* input = (const float*)d_in[0];
  const float* W_ih  = (const float*)d_in[1];
  const float* W_hh  = (const float*)d_in[2];
  const float* b_ih  = (const float*)d_in[3];
  const float* b_hh  = (const float*)d_in[4];
  const float* W_lin = (const float*)d_in[5];
  const float* b_lin = (const float*)d_in[6];
  float* out = (float*)d_out;

  char* ws = (char*)d_ws;
  const size_t XG_BYTES = (size_t)T_SEQ * G4 * sizeof(float);   // 128 MB
  float*    xg    = (float*)ws;
  float*    hbuf  = (float*)(ws + XG_BYTES);                    // 2*2048 f32
  unsigned* flags = (unsigned*)(ws + XG_BYTES + 2 * H_DIM * sizeof(float));

  // zero h0 buffer (h_{-1}=0), h1, and the 256 sync flags — every launch
  hipMemsetAsync(ws + XG_BYTES, 0, 2 * H_DIM * sizeof(float) + 256 * sizeof(unsigned), stream);

  gemm_xg<<<dim3(64, 32), 256, 0, stream>>>(input, W_ih, b_ih, b_hh, xg);
  lstm_seq<<<256, 512, 0, stream>>>(W_hh, xg, hbuf, flags);
  proj_out<<<128, 256, 0, stream>>>(W_lin, b_lin, hbuf, out);
}

// Round 4
// 13071.324 us; speedup vs baseline: 12.0206x; 1.9451x over previous
//
#include <hip/hip_runtime.h>
#include <math.h>

#define T_SEQ 4096
#define I_DIM 1024
#define H_DIM 2048
#define O_DIM 512
#define G4    8192   // 4*H

// ---------------------------------------------------------------------------
// Phase 1: xg[t, perm(r)] = sum_k input[t,k]*W_ih[r,k] + b_ih[r] + b_hh[r]
// perm(r): r = g*2048 + 8*q + j  ->  t*8192 + q*32 + g*8 + j
// so that LSTM block b (=q) reads its 32 gate values contiguously.
// Tiled fp32 GEMM: 128x128 tile, BK=16, 256 threads, 8x8 microtile.
// ---------------------------------------------------------------------------
__global__ __launch_bounds__(256) void gemm_xg(
    const float* __restrict__ A, const float* __restrict__ W,
    const float* __restrict__ b_ih, const float* __restrict__ b_hh,
    float* __restrict__ xg)
{
  __shared__ __align__(16) float As[16][132];
  __shared__ __align__(16) float Bs[16][132];
  const int tid = threadIdx.x;
  const int t0 = blockIdx.y * 128;
  const int r0 = blockIdx.x * 128;
  const int tx = tid & 15, ty = tid >> 4;

  float acc[8][8];
  #pragma unroll
  for (int i = 0; i < 8; ++i)
    #pragma unroll
    for (int j = 0; j < 8; ++j) acc[i][j] = 0.f;

  for (int k0 = 0; k0 < I_DIM; k0 += 16) {
    #pragma unroll
    for (int i = 0; i < 2; ++i) {
      int lin = tid + i * 256;     // 0..511
      int row = lin >> 2;          // 0..127
      int kq  = (lin & 3) << 2;    // 0,4,8,12
      float4 va = *(const float4*)&A[(size_t)(t0 + row) * I_DIM + k0 + kq];
      As[kq+0][row] = va.x; As[kq+1][row] = va.y; As[kq+2][row] = va.z; As[kq+3][row] = va.w;
      float4 vb = *(const float4*)&W[(size_t)(r0 + row) * I_DIM + k0 + kq];
      Bs[kq+0][row] = vb.x; Bs[kq+1][row] = vb.y; Bs[kq+2][row] = vb.z; Bs[kq+3][row] = vb.w;
    }
    __syncthreads();
    #pragma unroll
    for (int kk = 0; kk < 16; ++kk) {
      float4 a0 = *(const float4*)&As[kk][ty*8];
      float4 a1 = *(const float4*)&As[kk][ty*8+4];
      float4 b0 = *(const float4*)&Bs[kk][tx*8];
      float4 b1 = *(const float4*)&Bs[kk][tx*8+4];
      float av[8] = {a0.x,a0.y,a0.z,a0.w,a1.x,a1.y,a1.z,a1.w};
      float bv[8] = {b0.x,b0.y,b0.z,b0.w,b1.x,b1.y,b1.z,b1.w};
      #pragma unroll
      for (int i = 0; i < 8; ++i)
        #pragma unroll
        for (int j = 0; j < 8; ++j)
          acc[i][j] = fmaf(av[i], bv[j], acc[i][j]);
    }
    __syncthreads();
  }

  const int rbase = r0 + tx * 8;          // multiple of 8
  const int g = rbase >> 11;              // gate 0..3 (constant over 8 cols)
  const int q = (rbase & 2047) >> 3;      // 8-row group = LSTM block id
  float bias[8];
  #pragma unroll
  for (int j = 0; j < 8; ++j) bias[j] = b_ih[rbase + j] + b_hh[rbase + j];
  #pragma unroll
  for (int i = 0; i < 8; ++i) {
    int t = t0 + ty * 8 + i;
    float* dst = &xg[(size_t)t * G4 + q * 32 + g * 8];
    float4 o0 = make_float4(acc[i][0]+bias[0], acc[i][1]+bias[1], acc[i][2]+bias[2], acc[i][3]+bias[3]);
    float4 o1 = make_float4(acc[i][4]+bias[4], acc[i][5]+bias[5], acc[i][6]+bias[6], acc[i][7]+bias[7]);
    *(float4*)&dst[0] = o0;
    *(float4*)&dst[4] = o1;
  }
}

// fast activations (lane 0 only, but on the serial critical path)
__device__ __forceinline__ float sigf(float x) {
  return 1.f / (1.f + __expf(-x));
}
__device__ __forceinline__ float tanh_fast(float x) {
  return 1.f - 2.f / (__expf(2.f * x) + 1.f);   // saturates correctly
}

// ---------------------------------------------------------------------------
// Phase 2: persistent LSTM recurrence, self-announcing data (no flags).
// h element e of step t is an 8-byte pair (value, tag=t) in hbuf[t&1][e],
// written with ONE global_store_dwordx2 sc0 sc1 (aligned 8B = single-copy
// atomic). Wave w of block b owns element 8b+w (4 gate rows in registers).
// Per step:
//   1. each wave polls its 256-pair slice of h_t (2 x dwordx4 per lane,
//      sc0 sc1 = LLC-coherent) until all tags == t  — the poll IS the read
//   2. broadcast values into LDS buffer t&1, ONE __syncthreads
//   3. ds_read columns, 128 FMAs, butterfly-reduce 4 gate sums
//   4. lane 0: activations, c update, one packed (value,tag=t+1) store
// Double-buffer safety (B=2): a block overwrites h_t only at step t+1,
// which it reaches only after seeing ALL tags of h_{t+1}, which requires
// every block to have finished reading h_t. Same argument orders the two
// alternating LDS buffers around the single barrier. Zero fences, zero
// vmcnt drains, zero L2 maintenance in the loop.
// ---------------------------------------------------------------------------
__global__ __launch_bounds__(512, 2) void lstm_seq(
    const float* __restrict__ W_hh, const float* __restrict__ xg,
    uint2* __restrict__ hbuf /* 2 * 2048 (value,tag) pairs */)
{
  __shared__ __align__(16) float smem[21000];  // 84000 B -> forces 1 block/CU
  float* hsh = smem;                           // 2 x 2048 broadcast buffers

  const int tid  = threadIdx.x;
  const int b    = blockIdx.x;     // 0..255
  const int lane = tid & 63;
  const int w    = tid >> 6;       // wave id = h element index within block

  // Weights: 4 gate rows of h-element 8b+w; cols 4*lane + 256*k, k=0..7.
  float4 wt[4][8];
  #pragma unroll
  for (int g = 0; g < 4; ++g) {
    const float* wr = &W_hh[(size_t)(g * H_DIM + 8 * b + w) * H_DIM + 4 * lane];
    #pragma unroll
    for (int k = 0; k < 8; ++k) wt[g][k] = *(const float4*)&wr[256 * k];
  }

  float c_reg = 0.f;          // cell state (lane 0 of each wave)
  bool gaveup = false;        // hang safety valve

  // preload xg for t = 0 (uniform addresses; only lane 0 consumes)
  const float* xp0 = &xg[(size_t)0 * G4 + b * 32 + w];
  float xgi = xp0[0], xgf = xp0[8], xgg = xp0[16], xgo = xp0[24];

  for (int t = 0; t < T_SEQ; ++t) {
    const uint2* hb = hbuf + ((t & 1) << 11);     // pairs holding h_t
    const unsigned tag = (unsigned)t;

    // 1) poll my 4 pairs (16B + 16B) until all 4 tags == t
    const uint2* a0 = hb + 256 * w + 4 * lane;
    uint4 f0, f1;
    int tries = 0;
    for (;;) {
      asm volatile("global_load_dwordx4 %0, %2, off sc0 sc1\n\t"
                   "global_load_dwordx4 %1, %3, off sc0 sc1\n\t"
                   "s_waitcnt vmcnt(0)"
                   : "=&v"(f0), "=&v"(f1)
                   : "v"(a0), "v"(a0 + 2)
                   : "memory");
      bool ok = (f0.y == tag) & (f0.w == tag) & (f1.y == tag) & (f1.w == tag);
      if (__all(ok) || gaveup) break;
      if (++tries > (1 << 17)) { gaveup = true; break; }
    }

    // 2) broadcast values into this step's LDS buffer
    float* hd = hsh + ((t & 1) << 11);
    float4 hv4 = make_float4(__uint_as_float(f0.x), __uint_as_float(f0.z),
                             __uint_as_float(f1.x), __uint_as_float(f1.z));
    *(float4*)&hd[256 * w + 4 * lane] = hv4;

    // prefetch xg for step t+1 (independent; lands during dot/reduce)
    float nxi = 0.f, nxf = 0.f, nxg = 0.f, nxo = 0.f;
    if (t + 1 < T_SEQ) {
      const float* xp = &xg[(size_t)(t + 1) * G4 + b * 32 + w];
      nxi = xp[0]; nxf = xp[8]; nxg = xp[16]; nxo = xp[24];
    }

    __syncthreads();   // the ONE barrier per step

    // 3) dot products: 4 gate rows x 32 cols per lane
    float s0 = 0.f, s1 = 0.f, s2 = 0.f, s3 = 0.f;
    #pragma unroll
    for (int k = 0; k < 8; ++k) {
      float4 hv = *(const float4*)&hd[4 * lane + 256 * k];
      s0 = fmaf(wt[0][k].x, hv.x, s0); s0 = fmaf(wt[0][k].y, hv.y, s0);
      s0 = fmaf(wt[0][k].z, hv.z, s0); s0 = fmaf(wt[0][k].w, hv.w, s0);
      s1 = fmaf(wt[1][k].x, hv.x, s1); s1 = fmaf(wt[1][k].y, hv.y, s1);
      s1 = fmaf(wt[1][k].z, hv.z, s1); s1 = fmaf(wt[1][k].w, hv.w, s1);
      s2 = fmaf(wt[2][k].x, hv.x, s2); s2 = fmaf(wt[2][k].y, hv.y, s2);
      s2 = fmaf(wt[2][k].z, hv.z, s2); s2 = fmaf(wt[2][k].w, hv.w, s2);
      s3 = fmaf(wt[3][k].x, hv.x, s3); s3 = fmaf(wt[3][k].y, hv.y, s3);
      s3 = fmaf(wt[3][k].z, hv.z, s3); s3 = fmaf(wt[3][k].w, hv.w, s3);
    }

    // butterfly reduce 4 values across 64 lanes
    #pragma unroll
    for (int sh = 32; sh >= 1; sh >>= 1) {
      s0 += __shfl_xor(s0, sh, 64);
      s1 += __shfl_xor(s1, sh, 64);
      s2 += __shfl_xor(s2, sh, 64);
      s3 += __shfl_xor(s3, sh, 64);
    }

    // 4) lane 0: gate math + ONE packed (value, tag) store
    if (lane == 0) {
      float iv = sigf(s0 + xgi);
      float fv = sigf(s1 + xgf);
      float gv = tanh_fast(s2 + xgg);
      float ov = sigf(s3 + xgo);
      c_reg = fv * c_reg + iv * gv;
      float hv = ov * tanh_fast(c_reg);
      uint2 pv;
      pv.x = __float_as_uint(hv);
      pv.y = (unsigned)(t + 1);
      uint2* dst = hbuf + (((t + 1) & 1) << 11) + 8 * b + w;
      asm volatile("global_store_dwordx2 %0, %1, off sc0 sc1"
                   :: "v"(dst), "v"(pv) : "memory");
    }

    xgi = nxi; xgf = nxf; xgg = nxg; xgo = nxo;
  }
}

// ---------------------------------------------------------------------------
// Phase 3: out[o] = h_last . W_lin[o,:] + b_lin[o]. One wave per output.
// h_last = values of pairs in hbuf[0] (step 4095 writes parity 0).
// ---------------------------------------------------------------------------
__global__ __launch_bounds__(256) void proj_out(
    const float* __restrict__ W_lin, const float* __restrict__ b_lin,
    const uint2* __restrict__ hpairs, float* __restrict__ out)
{
  const int tid = threadIdx.x;
  const int lane = tid & 63;
  const int w4 = tid >> 6;
  const int o = blockIdx.x * 4 + w4;
  const float* wr = &W_lin[(size_t)o * H_DIM + 4 * lane];
  float s = 0.f;
  #pragma unroll
  for (int k = 0; k < 8; ++k) {
    float4 wv = *(const float4*)&wr[256 * k];
    uint4 p0 = *(const uint4*)&hpairs[4 * lane + 256 * k];       // v,t,v,t
    uint4 p1 = *(const uint4*)&hpairs[4 * lane + 256 * k + 2];   // v,t,v,t
    s = fmaf(wv.x, __uint_as_float(p0.x), s);
    s = fmaf(wv.y, __uint_as_float(p0.z), s);
    s = fmaf(wv.z, __uint_as_float(p1.x), s);
    s = fmaf(wv.w, __uint_as_float(p1.z), s);
  }
  #pragma unroll
  for (int sh = 32; sh >= 1; sh >>= 1) s += __shfl_xor(s, sh, 64);
  if (lane == 0) out[o] = s + b_lin[o];
}

// ---------------------------------------------------------------------------
extern "C" void kernel_launch(void* const* d_in, const int* in_sizes, int n_in,
                              void* d_out, int out_size, void* d_ws, size_t ws_size,
                              hipStream_t stream)
{
  const float* input = (const float*)d_in[0];
  const float* W_ih  = (const float*)d_in[1];
  const float* W_hh  = (const float*)d_in[2];
  const float* b_ih  = (const float*)d_in[3];
  const float* b_hh  = (const float*)d_in[4];
  const float* W_lin = (const float*)d_in[5];
  const float* b_lin = (const float*)d_in[6];
  float* out = (float*)d_out;

  char* ws = (char*)d_ws;
  const size_t XG_BYTES = (size_t)T_SEQ * G4 * sizeof(float);   // 128 MB
  float* xg   = (float*)ws;
  uint2* hbuf = (uint2*)(ws + XG_BYTES);   // 2 x 2048 (value,tag) pairs

  // zero both pair buffers: h_0 = 0 with tag 0 (= step-0 poll target)
  hipMemsetAsync(ws + XG_BYTES, 0, 2 * H_DIM * sizeof(uint2), stream);

  gemm_xg<<<dim3(64, 32), 256, 0, stream>>>(input, W_ih, b_ih, b_hh, xg);
  lstm_seq<<<256, 512, 0, stream>>>(W_hh, xg, hbuf);
  proj_out<<<128, 256, 0, stream>>>(W_lin, b_lin, hbuf, out);
}

// Round 5
// 11517.736 us; speedup vs baseline: 13.6420x; 1.1349x over previous
//
#include <hip/hip_runtime.h>
#include <math.h>

#define T_SEQ 4096
#define I_DIM 1024
#define H_DIM 2048
#define O_DIM 512
#define G4    8192   // 4*H

// ---------------------------------------------------------------------------
// Phase 1: xg[t, perm(r)] = sum_k input[t,k]*W_ih[r,k] + b_ih[r] + b_hh[r]
// perm(r): r = g*2048 + 8*q + j  ->  t*8192 + q*32 + g*8 + j
// so that LSTM block b (=q) reads its 32 gate values contiguously.
// Tiled fp32 GEMM: 128x128 tile, BK=16, 256 threads, 8x8 microtile.
// ---------------------------------------------------------------------------
__global__ __launch_bounds__(256) void gemm_xg(
    const float* __restrict__ A, const float* __restrict__ W,
    const float* __restrict__ b_ih, const float* __restrict__ b_hh,
    float* __restrict__ xg)
{
  __shared__ __align__(16) float As[16][132];
  __shared__ __align__(16) float Bs[16][132];
  const int tid = threadIdx.x;
  const int t0 = blockIdx.y * 128;
  const int r0 = blockIdx.x * 128;
  const int tx = tid & 15, ty = tid >> 4;

  float acc[8][8];
  #pragma unroll
  for (int i = 0; i < 8; ++i)
    #pragma unroll
    for (int j = 0; j < 8; ++j) acc[i][j] = 0.f;

  for (int k0 = 0; k0 < I_DIM; k0 += 16) {
    #pragma unroll
    for (int i = 0; i < 2; ++i) {
      int lin = tid + i * 256;     // 0..511
      int row = lin >> 2;          // 0..127
      int kq  = (lin & 3) << 2;    // 0,4,8,12
      float4 va = *(const float4*)&A[(size_t)(t0 + row) * I_DIM + k0 + kq];
      As[kq+0][row] = va.x; As[kq+1][row] = va.y; As[kq+2][row] = va.z; As[kq+3][row] = va.w;
      float4 vb = *(const float4*)&W[(size_t)(r0 + row) * I_DIM + k0 + kq];
      Bs[kq+0][row] = vb.x; Bs[kq+1][row] = vb.y; Bs[kq+2][row] = vb.z; Bs[kq+3][row] = vb.w;
    }
    __syncthreads();
    #pragma unroll
    for (int kk = 0; kk < 16; ++kk) {
      float4 a0 = *(const float4*)&As[kk][ty*8];
      float4 a1 = *(const float4*)&As[kk][ty*8+4];
      float4 b0 = *(const float4*)&Bs[kk][tx*8];
      float4 b1 = *(const float4*)&Bs[kk][tx*8+4];
      float av[8] = {a0.x,a0.y,a0.z,a0.w,a1.x,a1.y,a1.z,a1.w};
      float bv[8] = {b0.x,b0.y,b0.z,b0.w,b1.x,b1.y,b1.z,b1.w};
      #pragma unroll
      for (int i = 0; i < 8; ++i)
        #pragma unroll
        for (int j = 0; j < 8; ++j)
          acc[i][j] = fmaf(av[i], bv[j], acc[i][j]);
    }
    __syncthreads();
  }

  const int rbase = r0 + tx * 8;          // multiple of 8
  const int g = rbase >> 11;              // gate 0..3 (constant over 8 cols)
  const int q = (rbase & 2047) >> 3;      // 8-row group = LSTM block id
  float bias[8];
  #pragma unroll
  for (int j = 0; j < 8; ++j) bias[j] = b_ih[rbase + j] + b_hh[rbase + j];
  #pragma unroll
  for (int i = 0; i < 8; ++i) {
    int t = t0 + ty * 8 + i;
    float* dst = &xg[(size_t)t * G4 + q * 32 + g * 8];
    float4 o0 = make_float4(acc[i][0]+bias[0], acc[i][1]+bias[1], acc[i][2]+bias[2], acc[i][3]+bias[3]);
    float4 o1 = make_float4(acc[i][4]+bias[4], acc[i][5]+bias[5], acc[i][6]+bias[6], acc[i][7]+bias[7]);
    *(float4*)&dst[0] = o0;
    *(float4*)&dst[4] = o1;
  }
}

// fast activations (lane 0 only, but on the serial critical path)
__device__ __forceinline__ float sigf(float x) {
  return 1.f / (1.f + __expf(-x));
}
__device__ __forceinline__ float tanh_fast(float x) {
  return 1.f - 2.f / (__expf(2.f * x) + 1.f);   // saturates correctly
}

// ---------------------------------------------------------------------------
// Phase 2: persistent LSTM recurrence, self-announcing data (no flags),
// with NREP-way replication of the (value,tag) pairs to shard poll load.
// h element e of step t is an 8-byte pair (value, tag=t), written with one
// global_store_dwordx2 sc0 sc1 per replica (aligned 8B = single-copy
// atomic). Replica r of parity p lives at hbuf[p*nrep*2048 + r*2048 + e];
// replicas are 16KB apart -> different LLC channels. Consumer wave w of
// block b polls ONLY replica (b & (nrep-1)): same-line poll pressure drops
// from 256 waves to 256/nrep waves. Per step:
//   1. poll my 4 pairs of my replica slice until all tags == t (the poll
//      IS the read; own-store ack overlaps the poll-load RTT in vmcnt(0))
//   2. broadcast values into LDS buffer t&1, ONE __syncthreads
//   3. 128 FMAs + butterfly-reduce 4 gate sums
//   4. lane 0: activations, c update, nrep packed (value,tag) stores
// Double-buffer safety (per replica): a block overwrites replica r of h_t
// only at step t+1, reached only after its poll of h_{t+1} succeeded,
// which requires every block to have finished reading h_t. Zero fences,
// zero L2 maintenance in the loop.
// ---------------------------------------------------------------------------
__global__ __launch_bounds__(512, 2) void lstm_seq(
    const float* __restrict__ W_hh, const float* __restrict__ xg,
    uint2* __restrict__ hbuf, int nrep)
{
  __shared__ __align__(16) float smem[21000];  // 84000 B -> forces 1 block/CU
  float* hsh = smem;                           // 2 x 2048 broadcast buffers

  const int tid  = threadIdx.x;
  const int b    = blockIdx.x;     // 0..255
  const int lane = tid & 63;
  const int w    = tid >> 6;       // wave id = h element index within block
  const int pstr = nrep << 11;     // pairs per parity
  const int myrep = b & (nrep - 1);

  // Weights: 4 gate rows of h-element 8b+w; cols 4*lane + 256*k, k=0..7.
  float4 wt[4][8];
  #pragma unroll
  for (int g = 0; g < 4; ++g) {
    const float* wr = &W_hh[(size_t)(g * H_DIM + 8 * b + w) * H_DIM + 4 * lane];
    #pragma unroll
    for (int k = 0; k < 8; ++k) wt[g][k] = *(const float4*)&wr[256 * k];
  }

  float c_reg = 0.f;          // cell state (lane 0 of each wave)
  bool gaveup = false;        // hang safety valve

  // preload xg for t = 0 (uniform addresses; only lane 0 consumes)
  const float* xp0 = &xg[(size_t)0 * G4 + b * 32 + w];
  float xgi = xp0[0], xgf = xp0[8], xgg = xp0[16], xgo = xp0[24];

  for (int t = 0; t < T_SEQ; ++t) {
    const uint2* hb = hbuf + (t & 1) * pstr + (myrep << 11);  // my replica of h_t
    const unsigned tag = (unsigned)t;

    // 1) poll my 4 pairs (16B + 16B) until all 4 tags == t
    const uint2* a0 = hb + 256 * w + 4 * lane;
    uint4 f0, f1;
    int tries = 0;
    for (;;) {
      asm volatile("global_load_dwordx4 %0, %2, off sc0 sc1\n\t"
                   "global_load_dwordx4 %1, %3, off sc0 sc1\n\t"
                   "s_waitcnt vmcnt(0)"
                   : "=&v"(f0), "=&v"(f1)
                   : "v"(a0), "v"(a0 + 2)
                   : "memory");
      bool ok = (f0.y == tag) & (f0.w == tag) & (f1.y == tag) & (f1.w == tag);
      if (__all(ok) || gaveup) break;
      if (++tries > (1 << 17)) { gaveup = true; break; }
    }

    // 2) broadcast values into this step's LDS buffer
    float* hd = hsh + ((t & 1) << 11);
    float4 hv4 = make_float4(__uint_as_float(f0.x), __uint_as_float(f0.z),
                             __uint_as_float(f1.x), __uint_as_float(f1.z));
    *(float4*)&hd[256 * w + 4 * lane] = hv4;

    // prefetch xg for step t+1 (independent; consumed at loop tail so the
    // compiler's waitcnt for it lands off the poll path)
    float nxi = 0.f, nxf = 0.f, nxg = 0.f, nxo = 0.f;
    if (t + 1 < T_SEQ) {
      const float* xp = &xg[(size_t)(t + 1) * G4 + b * 32 + w];
      nxi = xp[0]; nxf = xp[8]; nxg = xp[16]; nxo = xp[24];
    }

    __syncthreads();   // the ONE barrier per step

    // 3) dot products: 4 gate rows x 32 cols per lane
    float s0 = 0.f, s1 = 0.f, s2 = 0.f, s3 = 0.f;
    #pragma unroll
    for (int k = 0; k < 8; ++k) {
      float4 hv = *(const float4*)&hd[4 * lane + 256 * k];
      s0 = fmaf(wt[0][k].x, hv.x, s0); s0 = fmaf(wt[0][k].y, hv.y, s0);
      s0 = fmaf(wt[0][k].z, hv.z, s0); s0 = fmaf(wt[0][k].w, hv.w, s0);
      s1 = fmaf(wt[1][k].x, hv.x, s1); s1 = fmaf(wt[1][k].y, hv.y, s1);
      s1 = fmaf(wt[1][k].z, hv.z, s1); s1 = fmaf(wt[1][k].w, hv.w, s1);
      s2 = fmaf(wt[2][k].x, hv.x, s2); s2 = fmaf(wt[2][k].y, hv.y, s2);
      s2 = fmaf(wt[2][k].z, hv.z, s2); s2 = fmaf(wt[2][k].w, hv.w, s2);
      s3 = fmaf(wt[3][k].x, hv.x, s3); s3 = fmaf(wt[3][k].y, hv.y, s3);
      s3 = fmaf(wt[3][k].w, hv.w, s3); s3 = fmaf(wt[3][k].z, hv.z, s3);
    }

    // butterfly reduce 4 values across 64 lanes
    #pragma unroll
    for (int sh = 32; sh >= 1; sh >>= 1) {
      s0 += __shfl_xor(s0, sh, 64);
      s1 += __shfl_xor(s1, sh, 64);
      s2 += __shfl_xor(s2, sh, 64);
      s3 += __shfl_xor(s3, sh, 64);
    }

    // 4) lane 0: gate math + nrep packed (value, tag) stores (one/replica)
    if (lane == 0) {
      float iv = sigf(s0 + xgi);
      float fv = sigf(s1 + xgf);
      float gv = tanh_fast(s2 + xgg);
      float ov = sigf(s3 + xgo);
      c_reg = fv * c_reg + iv * gv;
      float hv = ov * tanh_fast(c_reg);
      uint2 pv;
      pv.x = __float_as_uint(hv);
      pv.y = (unsigned)(t + 1);
      uint2* dst = hbuf + ((t + 1) & 1) * pstr + 8 * b + w;
      for (int r = 0; r < nrep; ++r) {
        asm volatile("global_store_dwordx2 %0, %1, off sc0 sc1"
                     :: "v"(dst), "v"(pv) : "memory");
        dst += 2048;
      }
    }

    xgi = nxi; xgf = nxf; xgg = nxg; xgo = nxo;
  }
}

// ---------------------------------------------------------------------------
// Phase 3: out[o] = h_last . W_lin[o,:] + b_lin[o]. One wave per output.
// h_last = values of replica-0 pairs at parity 0 (step 4095 writes par 0).
// ---------------------------------------------------------------------------
__global__ __launch_bounds__(256) void proj_out(
    const float* __restrict__ W_lin, const float* __restrict__ b_lin,
    const uint2* __restrict__ hpairs, float* __restrict__ out)
{
  const int tid = threadIdx.x;
  const int lane = tid & 63;
  const int w4 = tid >> 6;
  const int o = blockIdx.x * 4 + w4;
  const float* wr = &W_lin[(size_t)o * H_DIM + 4 * lane];
  float s = 0.f;
  #pragma unroll
  for (int k = 0; k < 8; ++k) {
    float4 wv = *(const float4*)&wr[256 * k];
    uint4 p0 = *(const uint4*)&hpairs[4 * lane + 256 * k];       // v,t,v,t
    uint4 p1 = *(const uint4*)&hpairs[4 * lane + 256 * k + 2];   // v,t,v,t
    s = fmaf(wv.x, __uint_as_float(p0.x), s);
    s = fmaf(wv.y, __uint_as_float(p0.z), s);
    s = fmaf(wv.z, __uint_as_float(p1.x), s);
    s = fmaf(wv.w, __uint_as_float(p1.z), s);
  }
  #pragma unroll
  for (int sh = 32; sh >= 1; sh >>= 1) s += __shfl_xor(s, sh, 64);
  if (lane == 0) out[o] = s + b_lin[o];
}

// ---------------------------------------------------------------------------
extern "C" void kernel_launch(void* const* d_in, const int* in_sizes, int n_in,
                              void* d_out, int out_size, void* d_ws, size_t ws_size,
                              hipStream_t stream)
{
  const float* input = (const float*)d_in[0];
  const float* W_ih  = (const float*)d_in[1];
  const float* W_hh  = (const float*)d_in[2];
  const float* b_ih  = (const float*)d_in[3];
  const float* b_hh  = (const float*)d_in[4];
  const float* W_lin = (const float*)d_in[5];
  const float* b_lin = (const float*)d_in[6];
  float* out = (float*)d_out;

  char* ws = (char*)d_ws;
  const size_t XG_BYTES = (size_t)T_SEQ * G4 * sizeof(float);   // 128 MB
  float* xg   = (float*)ws;
  uint2* hbuf = (uint2*)(ws + XG_BYTES);

  // 8 replicas if the workspace allows (2 parities x 8 replicas x 2048 pairs
  // x 8B = 256KB), else fall back to the round-4 single-copy layout.
  const size_t HB8 = 2ull * 8 * H_DIM * sizeof(uint2);
  int nrep = (ws_size >= XG_BYTES + HB8) ? 8 : 1;
  const size_t HB_BYTES = 2ull * nrep * H_DIM * sizeof(uint2);

  // zero all pair buffers: h_0 = 0 with tag 0 (= step-0 poll target)
  hipMemsetAsync(ws + XG_BYTES, 0, HB_BYTES, stream);

  gemm_xg<<<dim3(64, 32), 256, 0, stream>>>(input, W_ih, b_ih, b_hh, xg);
  lstm_seq<<<256, 512, 0, stream>>>(W_hh, xg, hbuf, nrep);
  proj_out<<<128, 256, 0, stream>>>(W_lin, b_lin, hbuf, out);
}